// Round 4
// baseline (314.281 us; speedup 1.0000x reference)
//
#include <hip/hip_runtime.h>
#include <math.h>

// Problem constants
#define NCASES   16
#define NPTS_BIG 65536
#define F1       512
#define OUT_B    4096

typedef __attribute__((ext_vector_type(8))) short  short8;   // 8 bf16 = 4 VGPR (MFMA A/B frag)
typedef __attribute__((ext_vector_type(4))) float  floatx4;  // MFMA C/D frag

__device__ __forceinline__ float silu_f(float x) {
    return x * __builtin_amdgcn_rcpf(1.0f + __expf(-x));
}

// RNE fp32->bf16 left in bits [31:16]
__device__ __forceinline__ unsigned f2bf_hi(float x) {
    unsigned u = __float_as_uint(x);
    return u + 0x7FFFu + ((u >> 16) & 1u);
}
__device__ __forceinline__ unsigned short f2bf(float x) {
    return (unsigned short)(f2bf_hi(x) >> 16);
}
// pack two bf16 (lo,hi) into one u32 via v_perm: {lo[23:16],lo[31:24],hi[23:16],hi[31:24]}
__device__ __forceinline__ unsigned pk2bf(float lo, float hi) {
    return __builtin_amdgcn_perm(f2bf_hi(hi), f2bf_hi(lo), 0x07060302u);
}

// Monotone float -> uint mapping (handles negatives) for atomicMax argmax.
__device__ __forceinline__ unsigned enc_f(float x) {
    unsigned u = __float_as_uint(x);
    return (u & 0x80000000u) ? ~u : (u | 0x80000000u);
}
__device__ __forceinline__ float dec_f(unsigned e) {
    unsigned u = (e & 0x80000000u) ? (e ^ 0x80000000u) : ~e;
    return __uint_as_float(u);
}

// force value to SGPR
__device__ __forceinline__ float sgpr_f(float x) {
    return __uint_as_float(__builtin_amdgcn_readfirstlane(__float_as_uint(x)));
}

// Pre-swizzle W11/W12 into MFMA B-fragment order (bf16) + zero the two argmax buffers.
// B-layout for 16x16x32: B[k = KT*32 + (lane>>4)*8 + j][n = lane&15].
// BcWs: [w(8)][NT(4)][KT(4)][lane(64)][j(8)]  (W12, 128 KB)
// BbWs: [w(8)][KT(2)][lane(64)][j(8)]         (W11, 16 KB)
__global__ void k_prep(const float* __restrict__ W11, const float* __restrict__ W12,
                       unsigned short* __restrict__ BbWs, unsigned short* __restrict__ BcWs,
                       unsigned long long* __restrict__ argBufs)
{
    int i = blockIdx.x * 256 + threadIdx.x;   // 65536 threads
    if (i < 16384) argBufs[i] = 0ull;         // argBuf + argBuf2
    {
        int j = i & 7, l = (i >> 3) & 63, t = i >> 9;     // t = w*16 + NT*4 + KT
        int KT = t & 3, NT = (t >> 2) & 3, w = t >> 4;
        int k = KT * 32 + (l >> 4) * 8 + j;
        int f = w * 64 + NT * 16 + (l & 15);
        BcWs[i] = f2bf(W12[(size_t)k * 512 + f]);
    }
    if (i < 8192) {
        int j = i & 7, l = (i >> 3) & 63, t = i >> 9;     // t = w*2 + KT
        int KT = t & 1, w = t >> 1;
        int k = KT * 32 + (l >> 4) * 8 + j;
        int f = w * 16 + (l & 15);
        BbWs[i] = f2bf(W11[(size_t)k * 128 + f]);
    }
}

// Fused mlp1 + per-feature argmax of PRE-ACTIVATION (silu monotone for x>=-1.278,
// silu(x)<0 for x<0, per-feature max pre-act > 0 w.o.p. -> argmax silu(z) == argmax z).
// b12 added after the max; silu applied downstream (k_head).
// Argmax in-loop: 7-bit (ch,MT,r) code REPLACES the candidate's low-7 mantissa bits
// (v_and_or_b32: (bits & ~127) | code; code = 127 - (ch<<4|MT<<2|r) so larger code =
// earlier point -> first-occurrence tie-break for positive winners), then pure fmax
// trees -- no cmp/cndmask in the hot loop. Perturbation <= 2^-17 relative, exact decode.
// gatherIdx != null: stage A reads point gatherIdx[c*512+p] (fused critical-point gather).
__global__ __launch_bounds__(512, 2)
void k_mlp1_argmax(const float* __restrict__ pts, int nPts, int chunksPerBlock,
                   const unsigned long long* __restrict__ gatherIdx,
                   const float* __restrict__ W10, const float* __restrict__ b10,
                   const float* __restrict__ b11, const float* __restrict__ b12,
                   const unsigned short* __restrict__ BbWs,
                   const unsigned short* __restrict__ BcWs,
                   unsigned long long* __restrict__ argOut)
{
    const int c   = blockIdx.y;
    const int tid = threadIdx.x;
    const int w   = tid >> 6;   // wave 0..7
    const int l   = tid & 63;   // lane
    const int lm  = l & 15;     // m/n within 16x16 tile
    const int q   = l >> 4;     // quad

    __shared__ __align__(16) unsigned short s_h0[64][72];   // bf16, stride 144B
    __shared__ __align__(16) unsigned short s_h1[64][136];  // bf16, stride 272B
    // ~26.9 KB LDS

    const int wf = __builtin_amdgcn_readfirstlane(w);   // wave-uniform

    // stage-A weights in SGPRs (no LDS, no per-chunk reloads)
    float wA0[8], wA1[8], wA2[8], bA[8];
    #pragma unroll
    for (int j = 0; j < 8; ++j) {
        wA0[j] = sgpr_f(W10[  0 + wf * 8 + j]);
        wA1[j] = sgpr_f(W10[ 64 + wf * 8 + j]);
        wA2[j] = sgpr_f(W10[128 + wf * 8 + j]);
        bA[j]  = sgpr_f(b10[       wf * 8 + j]);
    }

    // persistent B fragments (registers/AGPRs)
    short8 Bc[16];   // [NT*4+KT] for W12 slice
    #pragma unroll
    for (int t = 0; t < 16; ++t)
        Bc[t] = *(const short8*)(BcWs + (size_t)((wf * 16 + t) * 64 + l) * 8);
    short8 Bb[2];    // [KT] for W11 slice
    #pragma unroll
    for (int t = 0; t < 2; ++t)
        Bb[t] = *(const short8*)(BbWs + (size_t)((wf * 2 + t) * 64 + l) * 8);

    const float bias11 = b11[wf * 16 + lm];
    float bias12[4];
    #pragma unroll
    for (int NT = 0; NT < 4; ++NT) bias12[NT] = b12[wf * 64 + NT * 16 + lm];

    float bestv[4];
    #pragma unroll
    for (int NT = 0; NT < 4; ++NT) bestv[NT] = -INFINITY;

    const float* cpts = pts + (size_t)c * nPts * 3;

    for (int ch = 0; ch < chunksPerBlock; ++ch) {
        const int pbase = (blockIdx.x * chunksPerBlock + ch) * 64;

        // ---- stage A: h0[64][64] = silu(pts @ W10 + b10); lane = point, wave = 8 feats ----
        {
            float x, y, z;
            if (gatherIdx) {
                unsigned gi = ~(unsigned)(gatherIdx[(size_t)c * 512 + pbase + l] & 0xFFFFFFFFull);
                const float* sp = cpts + (size_t)gi * 3;
                x = sp[0]; y = sp[1]; z = sp[2];
            } else {
                const float* sp = cpts + (size_t)(pbase + l) * 3;
                x = sp[0]; y = sp[1]; z = sp[2];
            }
            float v[8];
            #pragma unroll
            for (int j = 0; j < 8; ++j) {
                float t = fmaf(z, wA2[j], bA[j]);
                t = fmaf(y, wA1[j], t);
                t = fmaf(x, wA0[j], t);
                v[j] = silu_f(t);
            }
            uint4 hv = { pk2bf(v[0], v[1]), pk2bf(v[2], v[3]),
                         pk2bf(v[4], v[5]), pk2bf(v[6], v[7]) };
            *(uint4*)&s_h0[l][wf * 8] = hv;   // 16B aligned: l*144 + wf*16
        }
        __syncthreads();   // also orders: all waves done stage C(ch-1) -> h1 writable

        // ---- stage B: h1[64][128] = silu(h0 @ W11 + b11); bias as MFMA C-init ----
        #pragma unroll
        for (int MT = 0; MT < 4; ++MT) {
            short8 a0 = *(const short8*)&s_h0[MT * 16 + lm][q * 8];        // A[m=lm][k=q*8+j]
            short8 a1 = *(const short8*)&s_h0[MT * 16 + lm][32 + q * 8];
            floatx4 acc = {bias11, bias11, bias11, bias11};
            acc = __builtin_amdgcn_mfma_f32_16x16x32_bf16(a0, Bb[0], acc, 0, 0, 0);
            acc = __builtin_amdgcn_mfma_f32_16x16x32_bf16(a1, Bb[1], acc, 0, 0, 0);
            #pragma unroll
            for (int r = 0; r < 4; ++r)   // C/D: row = q*4+r (point), col = lm (feature)
                s_h1[MT * 16 + q * 4 + r][wf * 16 + lm] = f2bf(silu_f(acc[r]));
        }
        __syncthreads();   // also orders: all waves done stage B -> h0 writable next chunk

        // ---- stage C: pre-act feats = h1 @ W12; code-in-mantissa fmax argmax ----
        const int cb0 = 127 - (ch << 4);
        #pragma unroll
        for (int MT = 0; MT < 4; ++MT) {
            short8 a[4];
            #pragma unroll
            for (int KT = 0; KT < 4; ++KT)
                a[KT] = *(const short8*)&s_h1[MT * 16 + lm][KT * 32 + q * 8];
            const int cbM = cb0 - (MT << 2);
            #pragma unroll
            for (int NT = 0; NT < 4; ++NT) {
                floatx4 acc = {0.f, 0.f, 0.f, 0.f};
                #pragma unroll
                for (int KT = 0; KT < 4; ++KT)
                    acc = __builtin_amdgcn_mfma_f32_16x16x32_bf16(a[KT], Bc[NT * 4 + KT], acc, 0, 0, 0);
                // (bits & ~127) | code  -> v_and_or_b32; decode is exact at flush
                float x0 = __uint_as_float((__float_as_uint(acc[0]) & 0xFFFFFF80u) | (unsigned)(cbM));
                float x1 = __uint_as_float((__float_as_uint(acc[1]) & 0xFFFFFF80u) | (unsigned)(cbM - 1));
                float x2 = __uint_as_float((__float_as_uint(acc[2]) & 0xFFFFFF80u) | (unsigned)(cbM - 2));
                float x3 = __uint_as_float((__float_as_uint(acc[3]) & 0xFFFFFF80u) | (unsigned)(cbM - 3));
                bestv[NT] = fmaxf(bestv[NT], fmaxf(fmaxf(x0, x1), fmaxf(x2, x3)));
            }
        }
    }

    // ---- flush: decode code, strip it, combine quads via shfl, add b12, atomicMax ----
    #pragma unroll
    for (int NT = 0; NT < 4; ++NT) {
        unsigned u = __float_as_uint(bestv[NT]);
        int t = 127 - (int)(u & 127u);            // = ch<<4 | MT<<2 | r  (exact)
        unsigned idx = (unsigned)((blockIdx.x * chunksPerBlock + (t >> 4)) * 64
                                  + ((t >> 2) & 3) * 16 + q * 4 + (t & 3));
        float v = __uint_as_float(u & 0xFFFFFF80u) + bias12[NT];
        #pragma unroll
        for (int m = 16; m <= 32; m <<= 1) {
            float    vo = __shfl_xor(v, m, 64);
            unsigned io = __shfl_xor(idx, m, 64);
            if (vo > v || (vo == v && io < idx)) { v = vo; idx = io; }
        }
        if (q == 0) {
            unsigned long long key = ((unsigned long long)enc_f(v) << 32)
                                   | (unsigned long long)(~idx);
            atomicMax(&argOut[(size_t)c * 512 + wf * 64 + NT * 16 + lm], key);
        }
    }
}

// Head: latent0 = silu(decoded max pre-act) -> silu(@W20+b20) -> @W21+b21. One block/case.
__global__ __launch_bounds__(256)
void k_head(const unsigned long long* __restrict__ argBuf2,
            const float* __restrict__ W20, const float* __restrict__ b20,
            const float* __restrict__ W21, const float* __restrict__ b21,
            float* __restrict__ latent)
{
    const int c = blockIdx.x, tid = threadIdx.x;
    __shared__ float l0[512];
    __shared__ float hh[256];
    l0[tid]       = silu_f(dec_f((unsigned)(argBuf2[(size_t)c * 512 + tid] >> 32)));
    l0[tid + 256] = silu_f(dec_f((unsigned)(argBuf2[(size_t)c * 512 + tid + 256] >> 32)));
    __syncthreads();
    float acc = b20[tid];
    for (int k = 0; k < 512; ++k) acc += l0[k] * W20[(size_t)k * 256 + tid];
    hh[tid] = silu_f(acc);
    __syncthreads();
    #pragma unroll
    for (int r = 0; r < 2; ++r) {
        int f = tid + r * 256;
        float a2 = b21[f];
        for (int k = 0; k < 256; ++k) a2 += hh[k] * W21[(size_t)k * 512 + f];
        latent[(size_t)c * 512 + f] = a2;
    }
}

// out[b][:] = latent[x[b]][:]
__global__ void k_scatter(const int* __restrict__ x,
                          const float* __restrict__ latent,
                          float* __restrict__ out)
{
    const int b = blockIdx.x, t = threadIdx.x;   // 128 threads, float4 each
    int cid = x[b];
    const float4* src = (const float4*)(latent + (size_t)cid * 512);
    float4* dst = (float4*)(out + (size_t)b * 512);
    dst[t] = src[t];
}

extern "C" void kernel_launch(void* const* d_in, const int* in_sizes, int n_in,
                              void* d_out, int out_size, void* d_ws, size_t ws_size,
                              hipStream_t stream)
{
    const float* pts = (const float*)d_in[0];
    const float* W10 = (const float*)d_in[1];
    const float* b10 = (const float*)d_in[2];
    const float* W11 = (const float*)d_in[3];
    const float* b11 = (const float*)d_in[4];
    const float* W12 = (const float*)d_in[5];
    const float* b12 = (const float*)d_in[6];
    const float* W20 = (const float*)d_in[7];
    const float* b20 = (const float*)d_in[8];
    const float* W21 = (const float*)d_in[9];
    const float* b21 = (const float*)d_in[10];
    const int*   x   = (const int*)d_in[11];
    float* out = (float*)d_out;

    // Workspace layout (re-poisoned every call -> rebuild every call):
    char* ws = (char*)d_ws;
    unsigned long long* argBuf  = (unsigned long long*)ws;              //  64 KB
    unsigned long long* argBuf2 = (unsigned long long*)(ws + 65536);    //  64 KB
    float* latent               = (float*)(ws + 131072);                //  32 KB
    unsigned short* BbWs        = (unsigned short*)(ws + 163840);       //  16 KB
    unsigned short* BcWs        = (unsigned short*)(ws + 180224);       // 128 KB (total 308 KB)

    // prep: swizzle weights to MFMA B-frag order + zero both argmax buffers
    k_prep<<<dim3(256), dim3(256), 0, stream>>>(W11, W12, BbWs, BcWs, argBuf);

    // Phase 1: big MLP + argmax over 65536 points/case
    k_mlp1_argmax<<<dim3(128, NCASES), dim3(512), 0, stream>>>(
        pts, NPTS_BIG, 8, nullptr, W10, b10, b11, b12, BbWs, BcWs, argBuf);

    // Phase 2+3 fused: MLP over 512 critical points/case (gather via argBuf) + max
    k_mlp1_argmax<<<dim3(8, NCASES), dim3(512), 0, stream>>>(
        pts, NPTS_BIG, 1, argBuf, W10, b10, b11, b12, BbWs, BcWs, argBuf2);

    // Phase 4: head MLP per case (applies silu to decoded max)
    k_head<<<dim3(NCASES), dim3(256), 0, stream>>>(argBuf2, W20, b20, W21, b21, latent);

    // Phase 5: scatter latent rows to output by case id
    k_scatter<<<dim3(OUT_B), dim3(128), 0, stream>>>(x, latent, out);
}

// Round 5
// 276.588 us; speedup vs baseline: 1.1363x; 1.1363x over previous
//
#include <hip/hip_runtime.h>
#include <math.h>

// Problem constants
#define NCASES   16
#define NPTS_BIG 65536
#define F1       512
#define OUT_B    4096

typedef __attribute__((ext_vector_type(8))) short  short8;   // 8 bf16 = 4 VGPR (MFMA A/B frag)
typedef __attribute__((ext_vector_type(4))) float  floatx4;  // MFMA C/D frag

__device__ __forceinline__ float silu_f(float x) {
    return x * __builtin_amdgcn_rcpf(1.0f + __expf(-x));
}

// RNE fp32->bf16 left in bits [31:16]
__device__ __forceinline__ unsigned f2bf_hi(float x) {
    unsigned u = __float_as_uint(x);
    return u + 0x7FFFu + ((u >> 16) & 1u);
}
__device__ __forceinline__ unsigned short f2bf(float x) {
    return (unsigned short)(f2bf_hi(x) >> 16);
}
// pack two bf16 (lo,hi) into one u32 via v_perm
__device__ __forceinline__ unsigned pk2bf(float lo, float hi) {
    return __builtin_amdgcn_perm(f2bf_hi(hi), f2bf_hi(lo), 0x07060302u);
}

// Monotone float -> uint mapping (handles negatives) for atomicMax argmax.
__device__ __forceinline__ unsigned enc_f(float x) {
    unsigned u = __float_as_uint(x);
    return (u & 0x80000000u) ? ~u : (u | 0x80000000u);
}
__device__ __forceinline__ float dec_f(unsigned e) {
    unsigned u = (e & 0x80000000u) ? (e ^ 0x80000000u) : ~e;
    return __uint_as_float(u);
}

// force value to SGPR
__device__ __forceinline__ float sgpr_f(float x) {
    return __uint_as_float(__builtin_amdgcn_readfirstlane(__float_as_uint(x)));
}

// Pre-swizzle W11/W12 into MFMA B-fragment order (bf16) + zero the two argmax buffers.
// B-layout for 16x16x32: B[k = KT*32 + (lane>>4)*8 + j][n = lane&15].
// BcWs: [w(8)][NT(4)][KT(4)][lane(64)][j(8)]  (W12, 128 KB)
// BbWs: [w(8)][KT(2)][lane(64)][j(8)]         (W11, 16 KB)
__global__ void k_prep(const float* __restrict__ W11, const float* __restrict__ W12,
                       unsigned short* __restrict__ BbWs, unsigned short* __restrict__ BcWs,
                       unsigned long long* __restrict__ argBufs)
{
    int i = blockIdx.x * 256 + threadIdx.x;   // 65536 threads
    if (i < 16384) argBufs[i] = 0ull;         // argBuf + argBuf2
    {
        int j = i & 7, l = (i >> 3) & 63, t = i >> 9;     // t = w*16 + NT*4 + KT
        int KT = t & 3, NT = (t >> 2) & 3, w = t >> 4;
        int k = KT * 32 + (l >> 4) * 8 + j;
        int f = w * 64 + NT * 16 + (l & 15);
        BcWs[i] = f2bf(W12[(size_t)k * 512 + f]);
    }
    if (i < 8192) {
        int j = i & 7, l = (i >> 3) & 63, t = i >> 9;     // t = w*2 + KT
        int KT = t & 1, w = t >> 1;
        int k = KT * 32 + (l >> 4) * 8 + j;
        int f = w * 16 + (l & 15);
        BbWs[i] = f2bf(W11[(size_t)k * 128 + f]);
    }
}

// Fused mlp1 + per-feature argmax of PRE-ACTIVATION (silu monotone for x>=-1.278,
// silu(x)<0 for x<0, per-feature max pre-act > 0 w.o.p. -> argmax silu(z) == argmax z).
// b12 added after the max; silu applied downstream (k_head).
// Argmax in-loop: 7-bit (ch,MT,r) code replaces the candidate's low-7 mantissa bits
// ((bits & ~127) | code; code = 127 - (ch<<4|MT<<2|r): larger code = earlier point ->
// first-occurrence tie-break for positive winners), then pure max3/max trees.
// GATHER: stage A reads point gatherIdx[c*512+p] (fused critical-point gather).
// __launch_bounds__(512,4): pin total regs <= 128 (64 VGPR + 64 AGPR for Bc) ->
// 2 blocks/CU. R4 lesson: 68 VGPR crossed the 128-reg cliff -> 1 block/CU -> +20% time.
template<bool GATHER>
__global__ __launch_bounds__(512, 4)
void k_mlp1_argmax(const float* __restrict__ pts, int nPts, int chunksPerBlock,
                   const unsigned long long* __restrict__ gatherIdx,
                   const float* __restrict__ W10, const float* __restrict__ b10,
                   const float* __restrict__ b11, const float* __restrict__ b12,
                   const unsigned short* __restrict__ BbWs,
                   const unsigned short* __restrict__ BcWs,
                   unsigned long long* __restrict__ argOut)
{
    const int c   = blockIdx.y;
    const int tid = threadIdx.x;
    const int w   = tid >> 6;   // wave 0..7
    const int l   = tid & 63;   // lane
    const int lm  = l & 15;     // m/n within 16x16 tile
    const int q   = l >> 4;     // quad

    __shared__ __align__(16) unsigned short s_h0[64][72];   // bf16, stride 144B
    __shared__ __align__(16) unsigned short s_h1[64][136];  // bf16, stride 272B
    // ~26.9 KB LDS -> 2 blocks/CU easily

    const int wf = __builtin_amdgcn_readfirstlane(w);   // wave-uniform

    // stage-A weights in SGPRs (no LDS, no per-chunk reloads)
    float wA0[8], wA1[8], wA2[8], bA[8];
    #pragma unroll
    for (int j = 0; j < 8; ++j) {
        wA0[j] = sgpr_f(W10[  0 + wf * 8 + j]);
        wA1[j] = sgpr_f(W10[ 64 + wf * 8 + j]);
        wA2[j] = sgpr_f(W10[128 + wf * 8 + j]);
        bA[j]  = sgpr_f(b10[       wf * 8 + j]);
    }

    // persistent B fragments (AGPR side of the unified file)
    short8 Bc[16];   // [NT*4+KT] for W12 slice
    #pragma unroll
    for (int t = 0; t < 16; ++t)
        Bc[t] = *(const short8*)(BcWs + (size_t)((wf * 16 + t) * 64 + l) * 8);
    short8 Bb[2];    // [KT] for W11 slice
    #pragma unroll
    for (int t = 0; t < 2; ++t)
        Bb[t] = *(const short8*)(BbWs + (size_t)((wf * 2 + t) * 64 + l) * 8);

    const float bias11 = b11[wf * 16 + lm];

    float bestv[4];
    #pragma unroll
    for (int NT = 0; NT < 4; ++NT) bestv[NT] = -INFINITY;

    const float* cpts = pts + (size_t)c * nPts * 3;

    for (int ch = 0; ch < chunksPerBlock; ++ch) {
        const int pbase = (blockIdx.x * chunksPerBlock + ch) * 64;

        // ---- stage A: h0[64][64] = silu(pts @ W10 + b10); lane = point, wave = 8 feats ----
        {
            float x, y, z;
            if (GATHER) {
                unsigned gi = ~(unsigned)(gatherIdx[(size_t)c * 512 + pbase + l] & 0xFFFFFFFFull);
                const float* sp = cpts + (size_t)gi * 3;
                x = sp[0]; y = sp[1]; z = sp[2];
            } else {
                const float* sp = cpts + (size_t)(pbase + l) * 3;
                x = sp[0]; y = sp[1]; z = sp[2];
            }
            float v[8];
            #pragma unroll
            for (int j = 0; j < 8; ++j) {
                float t = fmaf(z, wA2[j], bA[j]);
                t = fmaf(y, wA1[j], t);
                t = fmaf(x, wA0[j], t);
                v[j] = silu_f(t);
            }
            uint4 hv = { pk2bf(v[0], v[1]), pk2bf(v[2], v[3]),
                         pk2bf(v[4], v[5]), pk2bf(v[6], v[7]) };
            *(uint4*)&s_h0[l][wf * 8] = hv;   // 16B aligned: l*144 + wf*16
        }
        __syncthreads();   // also orders: all waves done stage C(ch-1) -> h1 writable

        // ---- stage B: h1[64][128] = silu(h0 @ W11 + b11); bias as MFMA C-init ----
        #pragma unroll
        for (int MT = 0; MT < 4; ++MT) {
            short8 a0 = *(const short8*)&s_h0[MT * 16 + lm][q * 8];        // A[m=lm][k=q*8+j]
            short8 a1 = *(const short8*)&s_h0[MT * 16 + lm][32 + q * 8];
            floatx4 acc = {bias11, bias11, bias11, bias11};
            acc = __builtin_amdgcn_mfma_f32_16x16x32_bf16(a0, Bb[0], acc, 0, 0, 0);
            acc = __builtin_amdgcn_mfma_f32_16x16x32_bf16(a1, Bb[1], acc, 0, 0, 0);
            #pragma unroll
            for (int r = 0; r < 4; ++r)   // C/D: row = q*4+r (point), col = lm (feature)
                s_h1[MT * 16 + q * 4 + r][wf * 16 + lm] = f2bf(silu_f(acc[r]));
        }
        __syncthreads();   // also orders: all waves done stage B -> h0 writable next chunk

        // ---- stage C: pre-act feats = h1 @ W12; code-in-mantissa max3 argmax ----
        const int cb0 = 127 - (ch << 4);
        #pragma unroll
        for (int MT = 0; MT < 4; ++MT) {
            short8 a[4];
            #pragma unroll
            for (int KT = 0; KT < 4; ++KT)
                a[KT] = *(const short8*)&s_h1[MT * 16 + lm][KT * 32 + q * 8];
            const int cbM = cb0 - (MT << 2);
            #pragma unroll
            for (int NT = 0; NT < 4; ++NT) {
                floatx4 acc = {0.f, 0.f, 0.f, 0.f};
                #pragma unroll
                for (int KT = 0; KT < 4; ++KT)
                    acc = __builtin_amdgcn_mfma_f32_16x16x32_bf16(a[KT], Bc[NT * 4 + KT], acc, 0, 0, 0);
                // (bits & ~127) | code  -> v_and_or_b32; decode exact at flush
                float x0 = __uint_as_float((__float_as_uint(acc[0]) & 0xFFFFFF80u) | (unsigned)(cbM));
                float x1 = __uint_as_float((__float_as_uint(acc[1]) & 0xFFFFFF80u) | (unsigned)(cbM - 1));
                float x2 = __uint_as_float((__float_as_uint(acc[2]) & 0xFFFFFF80u) | (unsigned)(cbM - 2));
                float x3 = __uint_as_float((__float_as_uint(acc[3]) & 0xFFFFFF80u) | (unsigned)(cbM - 3));
                // max3-shaped: v_max3(x0,x1,x2); v_max3(t,x3,bestv)
                float t0 = fmaxf(fmaxf(x0, x1), x2);
                bestv[NT] = fmaxf(fmaxf(t0, x3), bestv[NT]);
            }
        }
    }

    // ---- flush: decode code, strip it, combine quads via shfl, add b12, atomicMax ----
    #pragma unroll
    for (int NT = 0; NT < 4; ++NT) {
        unsigned u = __float_as_uint(bestv[NT]);
        int t = 127 - (int)(u & 127u);            // = ch<<4 | MT<<2 | r  (exact)
        unsigned idx = (unsigned)((blockIdx.x * chunksPerBlock + (t >> 4)) * 64
                                  + ((t >> 2) & 3) * 16 + q * 4 + (t & 3));
        float v = __uint_as_float(u & 0xFFFFFF80u) + b12[wf * 64 + NT * 16 + lm];
        #pragma unroll
        for (int m = 16; m <= 32; m <<= 1) {
            float    vo = __shfl_xor(v, m, 64);
            unsigned io = __shfl_xor(idx, m, 64);
            if (vo > v || (vo == v && io < idx)) { v = vo; idx = io; }
        }
        if (q == 0) {
            unsigned long long key = ((unsigned long long)enc_f(v) << 32)
                                   | (unsigned long long)(~idx);
            atomicMax(&argOut[(size_t)c * 512 + wf * 64 + NT * 16 + lm], key);
        }
    }
}

// Head: latent0 = silu(decoded max pre-act) -> silu(@W20+b20) -> @W21+b21. One block/case.
__global__ __launch_bounds__(256)
void k_head(const unsigned long long* __restrict__ argBuf2,
            const float* __restrict__ W20, const float* __restrict__ b20,
            const float* __restrict__ W21, const float* __restrict__ b21,
            float* __restrict__ latent)
{
    const int c = blockIdx.x, tid = threadIdx.x;
    __shared__ float l0[512];
    __shared__ float hh[256];
    l0[tid]       = silu_f(dec_f((unsigned)(argBuf2[(size_t)c * 512 + tid] >> 32)));
    l0[tid + 256] = silu_f(dec_f((unsigned)(argBuf2[(size_t)c * 512 + tid + 256] >> 32)));
    __syncthreads();
    float acc = b20[tid];
    for (int k = 0; k < 512; ++k) acc += l0[k] * W20[(size_t)k * 256 + tid];
    hh[tid] = silu_f(acc);
    __syncthreads();
    #pragma unroll
    for (int r = 0; r < 2; ++r) {
        int f = tid + r * 256;
        float a2 = b21[f];
        for (int k = 0; k < 256; ++k) a2 += hh[k] * W21[(size_t)k * 512 + f];
        latent[(size_t)c * 512 + f] = a2;
    }
}

// out[b][:] = latent[x[b]][:]
__global__ void k_scatter(const int* __restrict__ x,
                          const float* __restrict__ latent,
                          float* __restrict__ out)
{
    const int b = blockIdx.x, t = threadIdx.x;   // 128 threads, float4 each
    int cid = x[b];
    const float4* src = (const float4*)(latent + (size_t)cid * 512);
    float4* dst = (float4*)(out + (size_t)b * 512);
    dst[t] = src[t];
}

extern "C" void kernel_launch(void* const* d_in, const int* in_sizes, int n_in,
                              void* d_out, int out_size, void* d_ws, size_t ws_size,
                              hipStream_t stream)
{
    const float* pts = (const float*)d_in[0];
    const float* W10 = (const float*)d_in[1];
    const float* b10 = (const float*)d_in[2];
    const float* W11 = (const float*)d_in[3];
    const float* b11 = (const float*)d_in[4];
    const float* W12 = (const float*)d_in[5];
    const float* b12 = (const float*)d_in[6];
    const float* W20 = (const float*)d_in[7];
    const float* b20 = (const float*)d_in[8];
    const float* W21 = (const float*)d_in[9];
    const float* b21 = (const float*)d_in[10];
    const int*   x   = (const int*)d_in[11];
    float* out = (float*)d_out;

    // Workspace layout (re-poisoned every call -> rebuild every call):
    char* ws = (char*)d_ws;
    unsigned long long* argBuf  = (unsigned long long*)ws;              //  64 KB
    unsigned long long* argBuf2 = (unsigned long long*)(ws + 65536);    //  64 KB
    float* latent               = (float*)(ws + 131072);                //  32 KB
    unsigned short* BbWs        = (unsigned short*)(ws + 163840);       //  16 KB
    unsigned short* BcWs        = (unsigned short*)(ws + 180224);       // 128 KB (total 308 KB)

    // prep: swizzle weights to MFMA B-frag order + zero both argmax buffers
    k_prep<<<dim3(256), dim3(256), 0, stream>>>(W11, W12, BbWs, BcWs, argBuf);

    // Phase 1: big MLP + argmax over 65536 points/case
    k_mlp1_argmax<false><<<dim3(128, NCASES), dim3(512), 0, stream>>>(
        pts, NPTS_BIG, 8, nullptr, W10, b10, b11, b12, BbWs, BcWs, argBuf);

    // Phase 2+3 fused: MLP over 512 critical points/case (gather via argBuf) + max
    k_mlp1_argmax<true><<<dim3(8, NCASES), dim3(512), 0, stream>>>(
        pts, NPTS_BIG, 1, argBuf, W10, b10, b11, b12, BbWs, BcWs, argBuf2);

    // Phase 4: head MLP per case (applies silu to decoded max)
    k_head<<<dim3(NCASES), dim3(256), 0, stream>>>(argBuf2, W20, b20, W21, b21, latent);

    // Phase 5: scatter latent rows to output by case id
    k_scatter<<<dim3(OUT_B), dim3(128), 0, stream>>>(x, latent, out);
}

// Round 6
// 264.536 us; speedup vs baseline: 1.1880x; 1.0456x over previous
//
#include <hip/hip_runtime.h>
#include <math.h>

// Problem constants
#define NCASES   16
#define NPTS_BIG 65536
#define F1       512
#define OUT_B    4096

typedef __attribute__((ext_vector_type(8))) short  short8;   // 8 bf16 = 4 VGPR (MFMA A/B frag)
typedef __attribute__((ext_vector_type(4))) float  floatx4;  // MFMA C/D frag

__device__ __forceinline__ float silu_f(float x) {
    return x * __builtin_amdgcn_rcpf(1.0f + __expf(-x));
}

// RNE fp32->bf16 left in bits [31:16]  (used in one-time prep only)
__device__ __forceinline__ unsigned f2bf_hi(float x) {
    unsigned u = __float_as_uint(x);
    return u + 0x7FFFu + ((u >> 16) & 1u);
}
__device__ __forceinline__ unsigned short f2bf(float x) {
    return (unsigned short)(f2bf_hi(x) >> 16);
}
// RTZ pack: two f32 -> two bf16 in one v_perm (truncate mantissa; hot-loop path).
// dst = [lo.bf16, hi.bf16]: bytes {s1.b2, s1.b3, s0.b2, s0.b3}
__device__ __forceinline__ unsigned pk2bf_rtz(float lo, float hi) {
    return __builtin_amdgcn_perm(__float_as_uint(hi), __float_as_uint(lo), 0x07060302u);
}

// Monotone float -> uint mapping (handles negatives) for atomicMax argmax.
__device__ __forceinline__ unsigned enc_f(float x) {
    unsigned u = __float_as_uint(x);
    return (u & 0x80000000u) ? ~u : (u | 0x80000000u);
}
__device__ __forceinline__ float dec_f(unsigned e) {
    unsigned u = (e & 0x80000000u) ? (e ^ 0x80000000u) : ~e;
    return __uint_as_float(u);
}

// force value to SGPR
__device__ __forceinline__ float sgpr_f(float x) {
    return __uint_as_float(__builtin_amdgcn_readfirstlane(__float_as_uint(x)));
}

// Pre-swizzle W11/W12 into MFMA B-fragment order (bf16, RNE) + zero argmax buffers.
// B-layout for 16x16x32: B[k = KT*32 + (lane>>4)*8 + j][n = lane&15].
// BcWs: [w(8)][NT(4)][KT(4)][lane(64)][j(8)]  (W12, 128 KB)
// BbWs: [w(8)][KT(2)][lane(64)][j(8)]         (W11, 16 KB)
__global__ void k_prep(const float* __restrict__ W11, const float* __restrict__ W12,
                       unsigned short* __restrict__ BbWs, unsigned short* __restrict__ BcWs,
                       unsigned long long* __restrict__ argBufs)
{
    int i = blockIdx.x * 256 + threadIdx.x;   // 65536 threads
    if (i < 16384) argBufs[i] = 0ull;         // argBuf + argBuf2
    {
        int j = i & 7, l = (i >> 3) & 63, t = i >> 9;     // t = w*16 + NT*4 + KT
        int KT = t & 3, NT = (t >> 2) & 3, w = t >> 4;
        int k = KT * 32 + (l >> 4) * 8 + j;
        int f = w * 64 + NT * 16 + (l & 15);
        BcWs[i] = f2bf(W12[(size_t)k * 512 + f]);
    }
    if (i < 8192) {
        int j = i & 7, l = (i >> 3) & 63, t = i >> 9;     // t = w*2 + KT
        int KT = t & 1, w = t >> 1;
        int k = KT * 32 + (l >> 4) * 8 + j;
        int f = w * 16 + (l & 15);
        BbWs[i] = f2bf(W11[(size_t)k * 128 + f]);
    }
}

// Fused mlp1 + per-feature argmax of PRE-ACTIVATION (silu monotone for x>=-1.278,
// silu(x)<0 for x<0, per-feature max pre-act > 0 w.o.p. -> argmax silu(z) == argmax z).
// b12 added after the max; silu applied downstream (k_head).
// Argmax in-loop: 7-bit (ch,MT,r) code replaces the candidate's low-7 mantissa bits
// ((bits & ~127) | code; code = 127 - (ch<<4|MT<<2|r): larger code = earlier point ->
// first-occurrence tie-break for positive winners), then pure max3/max trees.
// h0/h1 stored as bf16-RTZ (raw fp32 hi-half: v_perm pack / d16_hi store, ~0 VALU) --
// one-sided 2^-9 avg bias, systematic ~0.2% on pre-acts, well under the 0.07 budget.
// GATHER: stage A reads point gatherIdx[c*512+p] (fused critical-point gather).
// __launch_bounds__(512,4): pin total regs <= 128 (56 VGPR + 64 AGPR Bc) -> 2 blocks/CU.
template<bool GATHER>
__global__ __launch_bounds__(512, 4)
void k_mlp1_argmax(const float* __restrict__ pts, int nPts, int chunksPerBlock,
                   const unsigned long long* __restrict__ gatherIdx,
                   const float* __restrict__ W10, const float* __restrict__ b10,
                   const float* __restrict__ b11, const float* __restrict__ b12,
                   const unsigned short* __restrict__ BbWs,
                   const unsigned short* __restrict__ BcWs,
                   unsigned long long* __restrict__ argOut)
{
    const int c   = blockIdx.y;
    const int tid = threadIdx.x;
    const int w   = tid >> 6;   // wave 0..7
    const int l   = tid & 63;   // lane
    const int lm  = l & 15;     // m/n within 16x16 tile
    const int q   = l >> 4;     // quad

    __shared__ __align__(16) unsigned short s_h0[64][72];   // bf16, stride 144B
    __shared__ __align__(16) unsigned short s_h1[64][136];  // bf16, stride 272B
    // ~26.9 KB LDS -> 2 blocks/CU easily

    const int wf = __builtin_amdgcn_readfirstlane(w);   // wave-uniform

    // stage-A weights in SGPRs (no LDS, no per-chunk reloads)
    float wA0[8], wA1[8], wA2[8], bA[8];
    #pragma unroll
    for (int j = 0; j < 8; ++j) {
        wA0[j] = sgpr_f(W10[  0 + wf * 8 + j]);
        wA1[j] = sgpr_f(W10[ 64 + wf * 8 + j]);
        wA2[j] = sgpr_f(W10[128 + wf * 8 + j]);
        bA[j]  = sgpr_f(b10[       wf * 8 + j]);
    }

    // persistent B fragments (AGPR side of the unified file)
    short8 Bc[16];   // [NT*4+KT] for W12 slice
    #pragma unroll
    for (int t = 0; t < 16; ++t)
        Bc[t] = *(const short8*)(BcWs + (size_t)((wf * 16 + t) * 64 + l) * 8);
    short8 Bb[2];    // [KT] for W11 slice
    #pragma unroll
    for (int t = 0; t < 2; ++t)
        Bb[t] = *(const short8*)(BbWs + (size_t)((wf * 2 + t) * 64 + l) * 8);

    const float bias11 = b11[wf * 16 + lm];

    float bestv[4];
    #pragma unroll
    for (int NT = 0; NT < 4; ++NT) bestv[NT] = -INFINITY;

    const float* cpts = pts + (size_t)c * nPts * 3;

    for (int ch = 0; ch < chunksPerBlock; ++ch) {
        const int pbase = (blockIdx.x * chunksPerBlock + ch) * 64;

        // ---- stage A: h0[64][64] = silu(pts @ W10 + b10); lane = point, wave = 8 feats ----
        {
            float x, y, z;
            if (GATHER) {
                unsigned gi = ~(unsigned)(gatherIdx[(size_t)c * 512 + pbase + l] & 0xFFFFFFFFull);
                const float* sp = cpts + (size_t)gi * 3;
                x = sp[0]; y = sp[1]; z = sp[2];
            } else {
                const float* sp = cpts + (size_t)(pbase + l) * 3;
                x = sp[0]; y = sp[1]; z = sp[2];
            }
            float v[8];
            #pragma unroll
            for (int j = 0; j < 8; ++j) {
                float t = fmaf(z, wA2[j], bA[j]);
                t = fmaf(y, wA1[j], t);
                t = fmaf(x, wA0[j], t);
                v[j] = silu_f(t);
            }
            uint4 hv = { pk2bf_rtz(v[0], v[1]), pk2bf_rtz(v[2], v[3]),
                         pk2bf_rtz(v[4], v[5]), pk2bf_rtz(v[6], v[7]) };
            *(uint4*)&s_h0[l][wf * 8] = hv;   // 16B aligned: l*144 + wf*16
        }
        __syncthreads();   // also orders: all waves done stage C(ch-1) -> h1 writable

        // ---- stage B: h1[64][128] = silu(h0 @ W11 + b11); bias as MFMA C-init ----
        #pragma unroll
        for (int MT = 0; MT < 4; ++MT) {
            short8 a0 = *(const short8*)&s_h0[MT * 16 + lm][q * 8];        // A[m=lm][k=q*8+j]
            short8 a1 = *(const short8*)&s_h0[MT * 16 + lm][32 + q * 8];
            floatx4 acc = {bias11, bias11, bias11, bias11};
            acc = __builtin_amdgcn_mfma_f32_16x16x32_bf16(a0, Bb[0], acc, 0, 0, 0);
            acc = __builtin_amdgcn_mfma_f32_16x16x32_bf16(a1, Bb[1], acc, 0, 0, 0);
            #pragma unroll
            for (int r = 0; r < 4; ++r) {  // C/D: row = q*4+r (point), col = lm (feature)
                // RTZ bf16 store: raw hi-half -> ds_write_b16_d16_hi, no round VALU
                unsigned uv = __float_as_uint(silu_f(acc[r]));
                s_h1[MT * 16 + q * 4 + r][wf * 16 + lm] = (unsigned short)(uv >> 16);
            }
        }
        __syncthreads();   // also orders: all waves done stage B -> h0 writable next chunk

        // ---- stage C: pre-act feats = h1 @ W12; code-in-mantissa max3 argmax ----
        const int cb0 = 127 - (ch << 4);
        #pragma unroll
        for (int MT = 0; MT < 4; ++MT) {
            short8 a[4];
            #pragma unroll
            for (int KT = 0; KT < 4; ++KT)
                a[KT] = *(const short8*)&s_h1[MT * 16 + lm][KT * 32 + q * 8];
            const int cbM = cb0 - (MT << 2);
            #pragma unroll
            for (int NT = 0; NT < 4; ++NT) {
                floatx4 acc = {0.f, 0.f, 0.f, 0.f};
                #pragma unroll
                for (int KT = 0; KT < 4; ++KT)
                    acc = __builtin_amdgcn_mfma_f32_16x16x32_bf16(a[KT], Bc[NT * 4 + KT], acc, 0, 0, 0);
                // (bits & ~127) | code  -> v_and_or_b32; decode exact at flush
                float x0 = __uint_as_float((__float_as_uint(acc[0]) & 0xFFFFFF80u) | (unsigned)(cbM));
                float x1 = __uint_as_float((__float_as_uint(acc[1]) & 0xFFFFFF80u) | (unsigned)(cbM - 1));
                float x2 = __uint_as_float((__float_as_uint(acc[2]) & 0xFFFFFF80u) | (unsigned)(cbM - 2));
                float x3 = __uint_as_float((__float_as_uint(acc[3]) & 0xFFFFFF80u) | (unsigned)(cbM - 3));
                // 2x v_max3: max3(x0,x1,x2) then max3(t0,x3,bestv)
                float t0 = fmaxf(fmaxf(x0, x1), x2);
                bestv[NT] = fmaxf(fmaxf(t0, x3), bestv[NT]);
            }
        }
    }

    // ---- flush: decode code, strip it, combine quads via shfl, add b12, atomicMax ----
    #pragma unroll
    for (int NT = 0; NT < 4; ++NT) {
        unsigned u = __float_as_uint(bestv[NT]);
        int t = 127 - (int)(u & 127u);            // = ch<<4 | MT<<2 | r  (exact)
        unsigned idx = (unsigned)((blockIdx.x * chunksPerBlock + (t >> 4)) * 64
                                  + ((t >> 2) & 3) * 16 + q * 4 + (t & 3));
        float v = __uint_as_float(u & 0xFFFFFF80u) + b12[wf * 64 + NT * 16 + lm];
        #pragma unroll
        for (int m = 16; m <= 32; m <<= 1) {
            float    vo = __shfl_xor(v, m, 64);
            unsigned io = __shfl_xor(idx, m, 64);
            if (vo > v || (vo == v && io < idx)) { v = vo; idx = io; }
        }
        if (q == 0) {
            unsigned long long key = ((unsigned long long)enc_f(v) << 32)
                                   | (unsigned long long)(~idx);
            atomicMax(&argOut[(size_t)c * 512 + wf * 64 + NT * 16 + lm], key);
        }
    }
}

// Head: latent0 = silu(decoded max pre-act) -> silu(@W20+b20) -> @W21+b21. One block/case.
__global__ __launch_bounds__(256)
void k_head(const unsigned long long* __restrict__ argBuf2,
            const float* __restrict__ W20, const float* __restrict__ b20,
            const float* __restrict__ W21, const float* __restrict__ b21,
            float* __restrict__ latent)
{
    const int c = blockIdx.x, tid = threadIdx.x;
    __shared__ float l0[512];
    __shared__ float hh[256];
    l0[tid]       = silu_f(dec_f((unsigned)(argBuf2[(size_t)c * 512 + tid] >> 32)));
    l0[tid + 256] = silu_f(dec_f((unsigned)(argBuf2[(size_t)c * 512 + tid + 256] >> 32)));
    __syncthreads();
    float acc = b20[tid];
    for (int k = 0; k < 512; ++k) acc += l0[k] * W20[(size_t)k * 256 + tid];
    hh[tid] = silu_f(acc);
    __syncthreads();
    #pragma unroll
    for (int r = 0; r < 2; ++r) {
        int f = tid + r * 256;
        float a2 = b21[f];
        for (int k = 0; k < 256; ++k) a2 += hh[k] * W21[(size_t)k * 512 + f];
        latent[(size_t)c * 512 + f] = a2;
    }
}

// out[b][:] = latent[x[b]][:]
__global__ void k_scatter(const int* __restrict__ x,
                          const float* __restrict__ latent,
                          float* __restrict__ out)
{
    const int b = blockIdx.x, t = threadIdx.x;   // 128 threads, float4 each
    int cid = x[b];
    const float4* src = (const float4*)(latent + (size_t)cid * 512);
    float4* dst = (float4*)(out + (size_t)b * 512);
    dst[t] = src[t];
}

extern "C" void kernel_launch(void* const* d_in, const int* in_sizes, int n_in,
                              void* d_out, int out_size, void* d_ws, size_t ws_size,
                              hipStream_t stream)
{
    const float* pts = (const float*)d_in[0];
    const float* W10 = (const float*)d_in[1];
    const float* b10 = (const float*)d_in[2];
    const float* W11 = (const float*)d_in[3];
    const float* b11 = (const float*)d_in[4];
    const float* W12 = (const float*)d_in[5];
    const float* b12 = (const float*)d_in[6];
    const float* W20 = (const float*)d_in[7];
    const float* b20 = (const float*)d_in[8];
    const float* W21 = (const float*)d_in[9];
    const float* b21 = (const float*)d_in[10];
    const int*   x   = (const int*)d_in[11];
    float* out = (float*)d_out;

    // Workspace layout (re-poisoned every call -> rebuild every call):
    char* ws = (char*)d_ws;
    unsigned long long* argBuf  = (unsigned long long*)ws;              //  64 KB
    unsigned long long* argBuf2 = (unsigned long long*)(ws + 65536);    //  64 KB
    float* latent               = (float*)(ws + 131072);                //  32 KB
    unsigned short* BbWs        = (unsigned short*)(ws + 163840);       //  16 KB
    unsigned short* BcWs        = (unsigned short*)(ws + 180224);       // 128 KB (total 308 KB)

    // prep: swizzle weights to MFMA B-frag order + zero both argmax buffers
    k_prep<<<dim3(256), dim3(256), 0, stream>>>(W11, W12, BbWs, BcWs, argBuf);

    // Phase 1: big MLP + argmax over 65536 points/case
    k_mlp1_argmax<false><<<dim3(128, NCASES), dim3(512), 0, stream>>>(
        pts, NPTS_BIG, 8, nullptr, W10, b10, b11, b12, BbWs, BcWs, argBuf);

    // Phase 2+3 fused: MLP over 512 critical points/case (gather via argBuf) + max
    k_mlp1_argmax<true><<<dim3(8, NCASES), dim3(512), 0, stream>>>(
        pts, NPTS_BIG, 1, argBuf, W10, b10, b11, b12, BbWs, BcWs, argBuf2);

    // Phase 4: head MLP per case (applies silu to decoded max)
    k_head<<<dim3(NCASES), dim3(256), 0, stream>>>(argBuf2, W20, b20, W21, b21, latent);

    // Phase 5: scatter latent rows to output by case id
    k_scatter<<<dim3(OUT_B), dim3(128), 0, stream>>>(x, latent, out);
}